// Round 1
// 174.078 us; speedup vs baseline: 1.0199x; 1.0199x over previous
//
#include <hip/hip_runtime.h>

// BiasedCrossAttention B=2, LQ=LK=1024, D=1024, H=16, DH=64. fp32 in/out.
// R7: attn restructured for occupancy. Old: khalf waves owned disjoint 512-key
//     ranges -> 4 resident 64x64 tiles (64 KB KV) + 8 KB P = 72 KB LDS = 2
//     blocks/CU = 8 waves/CU; MfmaUtil 6.8%, VALU 36%, Occ 18% (latency-bound).
//     New: khalf splits 32 keys WITHIN a shared 64-key tile -> KV dbuf 32 KB;
//     64 q-rows/block (8 waves = 4 qsub x 2 khalf), grid (16,32); LDS 40 KB ->
//     16 waves/CU. Bias premasked fp16 in log2-domain (cvt_bias into dead k16)
//     -> no mask loads/cndmask, bare v_exp_f32, half the bias cache traffic.
// ws (halves, 32 MB): q16|k16|v16 (2M ea) | Qh|Kh|Vt (2M ea) | W16 (4x1M).
// k16+v16 dead after QKV projections; k16 reused for premasked bias (4 MB).

typedef _Float16 half8 __attribute__((ext_vector_type(8)));
typedef _Float16 half4_t __attribute__((ext_vector_type(4)));
typedef float f32x4 __attribute__((ext_vector_type(4)));

#define MFMA16(a, b, c) __builtin_amdgcn_mfma_f32_16x16x32_f16((a), (b), (c), 0, 0, 0)

#define WAITCNT_VM(n) asm volatile("s_waitcnt vmcnt(" #n ")" ::: "memory")
#define WAITCNT_LGKM0() asm volatile("s_waitcnt lgkmcnt(0)" ::: "memory")
#define RAW_BARRIER() asm volatile("s_barrier" ::: "memory")
#define EXP2F(x) __builtin_amdgcn_exp2f(x)

__device__ __forceinline__ void gload16(const void* g, void* l) {
  __builtin_amdgcn_global_load_lds(
      (const __attribute__((address_space(1))) unsigned int*)g,
      (__attribute__((address_space(3))) unsigned int*)l, 16, 0, 0);
}

// Rows of 64 halves (8 x 16B chunks), physical chunk = logical ^ (row & 7).
__device__ __forceinline__ half8 frag_ld(const _Float16* t, int row, int ck) {
  return *(const half8*)(t + row * 64 + (((ck ^ (row & 7)) << 3)));
}

// ------------------------------------------------- cvt fp32->fp16 (acts + weights)
__global__ __launch_bounds__(256) void cvt_f32_f16(
    const float* __restrict__ q, const float* __restrict__ k, const float* __restrict__ v,
    const float* __restrict__ Wq, const float* __restrict__ Wk,
    const float* __restrict__ Wv, const float* __restrict__ Wo,
    _Float16* __restrict__ q16, _Float16* __restrict__ k16, _Float16* __restrict__ v16,
    _Float16* __restrict__ w16) {
  const int y = blockIdx.y;
  if (y >= 3 && blockIdx.x >= 512) return;  // weights are 1M elems (512 blocks)
  const float* s;
  _Float16* d;
  const size_t M = (size_t)1024 * 1024;
  switch (y) {
    case 0: s = q;  d = q16; break;
    case 1: s = k;  d = k16; break;
    case 2: s = v;  d = v16; break;
    case 3: s = Wq; d = w16; break;
    case 4: s = Wk; d = w16 + M; break;
    case 5: s = Wv; d = w16 + 2 * M; break;
    default: s = Wo; d = w16 + 3 * M; break;
  }
  const size_t i = ((size_t)blockIdx.x * 256 + threadIdx.x) * 8;
  const float4 a = *(const float4*)(s + i);
  const float4 bvv = *(const float4*)(s + i + 4);
  half8 h;
  h[0] = (_Float16)a.x; h[1] = (_Float16)a.y; h[2] = (_Float16)a.z; h[3] = (_Float16)a.w;
  h[4] = (_Float16)bvv.x; h[5] = (_Float16)bvv.y; h[6] = (_Float16)bvv.z; h[7] = (_Float16)bvv.w;
  *(half8*)(d + i) = h;
}

// ------------------------------------------------- bias: mask-fold + log2-prescale
// biasC[b,q,k] = mask[b,k] ? -30000 : bias * log2(e)  (fp16). attn then runs
// softmax entirely in base-2 (v_exp_f32 is exp2 natively).
__global__ __launch_bounds__(256) void cvt_bias(
    const float* __restrict__ biasL, const int* __restrict__ kpm,
    _Float16* __restrict__ biasC) {
  const size_t i = ((size_t)blockIdx.x * 256 + threadIdx.x) * 8;
  const int b = (int)(i >> 20);
  const int kk = (int)(i & 1023);
  const int* mrow = kpm + (b << 10) + kk;
  const float4 b0 = *(const float4*)(biasL + i);
  const float4 b1 = *(const float4*)(biasL + i + 4);
  const int4 m0 = *(const int4*)mrow;
  const int4 m1 = *(const int4*)(mrow + 4);
  const float sc = 1.44269504f;
  half8 h;
  h[0] = m0.x ? (_Float16)-30000.f : (_Float16)(b0.x * sc);
  h[1] = m0.y ? (_Float16)-30000.f : (_Float16)(b0.y * sc);
  h[2] = m0.z ? (_Float16)-30000.f : (_Float16)(b0.z * sc);
  h[3] = m0.w ? (_Float16)-30000.f : (_Float16)(b0.w * sc);
  h[4] = m1.x ? (_Float16)-30000.f : (_Float16)(b1.x * sc);
  h[5] = m1.y ? (_Float16)-30000.f : (_Float16)(b1.y * sc);
  h[6] = m1.z ? (_Float16)-30000.f : (_Float16)(b1.z * sc);
  h[7] = m1.w ? (_Float16)-30000.f : (_Float16)(b1.w * sc);
  *(half8*)(biasC + i) = h;
}

// ------------------------------------------------- pipelined GEMM C = X @ W^T + bias
// BM=64, BN=128, BK=64, 4 waves (2x2): wave tile 32x64 (2x4 MFMA tiles).
// Double-buffered LDS (48 KB = 3 blocks/CU); per-iter vmcnt(6) gate (6 DMA/thread).
__global__ __launch_bounds__(256) void mmp(
    const _Float16* __restrict__ Aq, const _Float16* __restrict__ Ak,
    const _Float16* __restrict__ Av, const _Float16* __restrict__ W16,
    const float* __restrict__ c0, const float* __restrict__ c1,
    const float* __restrict__ c2, _Float16* __restrict__ Dq,
    _Float16* __restrict__ Dk, _Float16* __restrict__ Dvt,
    float* __restrict__ Df, int is_final) {
  __shared__ __align__(16) _Float16 lds[24576];  // 2 x (A 4096 | B 8192); z==2 reuse Ct[128][72]

  const int tid = threadIdx.x;
  const int wv = tid >> 6, ln = tid & 63;
  const int quad = ln >> 4, col = ln & 15;
  const int wm = wv >> 1, wn = wv & 1;
  const int n0 = blockIdx.x * 128;
  const int m0 = blockIdx.y * 64;
  const int z = blockIdx.z;

  const _Float16* A = (z == 0) ? Aq : (z == 1) ? Ak : Av;
  const _Float16* Bw = W16 + (size_t)z * 1024 * 1024;
  const float* bias = (z == 0) ? c0 : (z == 1) ? c1 : c2;

  // stage tile k0 into buffer buf: chunks 0..511 = A (64 rows), 512..1535 = B (128 rows)
  auto stage = [&](int buf, int k0) {
#pragma unroll
    for (int j = 0; j < 6; ++j) {
      const int ci = j * 256 + tid;
      const _Float16* src;
      if (ci < 512) {
        const int row = ci >> 3, lc = (ci & 7) ^ (row & 7);
        src = A + (size_t)(m0 + row) * 1024 + k0 + lc * 8;
      } else {
        const int di = ci - 512;
        const int row = di >> 3, lc = (di & 7) ^ (row & 7);
        src = Bw + (size_t)(n0 + row) * 1024 + k0 + lc * 8;
      }
      gload16(src, lds + buf * 12288 + (j * 256 + wv * 64) * 8);  // A at +0, B at +4096
    }
  };

  const f32x4 zero4 = {0.f, 0.f, 0.f, 0.f};
  f32x4 acc[2][4];
#pragma unroll
  for (int i = 0; i < 2; ++i)
#pragma unroll
    for (int j = 0; j < 4; ++j) acc[i][j] = zero4;

  stage(0, 0);
  for (int i = 0; i < 15; ++i) {
    stage((i + 1) & 1, (i + 1) * 64);
    WAITCNT_VM(6);   // tile i landed (for this wave); prefetch i+1 stays in flight
    RAW_BARRIER();   // tile i landed for all waves
    const _Float16* As = lds + (i & 1) * 12288;
    const _Float16* Bs = As + 4096;
    half8 af[2][2], bf[2][4];
#pragma unroll
    for (int kk = 0; kk < 2; ++kk) {
#pragma unroll
      for (int mi = 0; mi < 2; ++mi)
        af[kk][mi] = frag_ld(As, wm * 32 + mi * 16 + col, kk * 4 + quad);
#pragma unroll
      for (int ni = 0; ni < 4; ++ni)
        bf[kk][ni] = frag_ld(Bs, wn * 64 + ni * 16 + col, kk * 4 + quad);
    }
    WAITCNT_LGKM0();
    RAW_BARRIER();   // all waves done reading buf (i&1) -> safe to DMA over next iter
#pragma unroll
    for (int kk = 0; kk < 2; ++kk)
#pragma unroll
      for (int mi = 0; mi < 2; ++mi)
#pragma unroll
        for (int ni = 0; ni < 4; ++ni)
          acc[mi][ni] = MFMA16(af[kk][mi], bf[kk][ni], acc[mi][ni]);
  }
  {  // last tile (15), buffer 1; no further staging
    WAITCNT_VM(0);
    RAW_BARRIER();
    const _Float16* As = lds + 12288;
    const _Float16* Bs = As + 4096;
#pragma unroll
    for (int kk = 0; kk < 2; ++kk) {
      half8 af[2], bf[4];
#pragma unroll
      for (int mi = 0; mi < 2; ++mi)
        af[mi] = frag_ld(As, wm * 32 + mi * 16 + col, kk * 4 + quad);
#pragma unroll
      for (int ni = 0; ni < 4; ++ni)
        bf[ni] = frag_ld(Bs, wn * 64 + ni * 16 + col, kk * 4 + quad);
#pragma unroll
      for (int mi = 0; mi < 2; ++mi)
#pragma unroll
        for (int ni = 0; ni < 4; ++ni)
          acc[mi][ni] = MFMA16(af[mi], bf[ni], acc[mi][ni]);
    }
  }

  float bv[4];
#pragma unroll
  for (int ni = 0; ni < 4; ++ni) bv[ni] = bias[n0 + wn * 64 + ni * 16 + col];

  if (is_final) {
#pragma unroll
    for (int mi = 0; mi < 2; ++mi) {
      const int m_g = m0 + wm * 32 + mi * 16 + quad * 4;
#pragma unroll
      for (int ni = 0; ni < 4; ++ni) {
        const int n_g = n0 + wn * 64 + ni * 16 + col;
#pragma unroll
        for (int r = 0; r < 4; ++r)
          Df[(size_t)(m_g + r) * 1024 + n_g] = acc[mi][ni][r] + bv[ni];
      }
    }
  } else if (z < 2) {
    _Float16* D = z ? Dk : Dq;
#pragma unroll
    for (int mi = 0; mi < 2; ++mi) {
      const int m_g = m0 + wm * 32 + mi * 16 + quad * 4;
#pragma unroll
      for (int ni = 0; ni < 4; ++ni) {
        const int n_g = n0 + wn * 64 + ni * 16 + col;
        const int h = n_g >> 6, dh = n_g & 63;
#pragma unroll
        for (int r = 0; r < 4; ++r) {
          const int b = (m_g + r) >> 10, l = (m_g + r) & 1023;
          D[((size_t)((b * 16 + h) * 1024) + l) * 64 + dh] =
              (_Float16)(acc[mi][ni][r] + bv[ni]);
        }
      }
    }
  } else {
    // transpose 64x128 through LDS -> Vt[bh][dh][l]
    __syncthreads();
    _Float16* Ct = lds;  // [128][72], 72*2B=144B row stride keeps 16B alignment
#pragma unroll
    for (int mi = 0; mi < 2; ++mi) {
      const int ml = wm * 32 + mi * 16 + quad * 4;
#pragma unroll
      for (int ni = 0; ni < 4; ++ni) {
        const int nl = wn * 64 + ni * 16 + col;
#pragma unroll
        for (int r = 0; r < 4; ++r)
          Ct[(size_t)nl * 72 + ml + r] = (_Float16)(acc[mi][ni][r] + bv[ni]);
      }
    }
    __syncthreads();
#pragma unroll
    for (int it = 0; it < 4; ++it) {
      const int ci = it * 256 + tid;
      const int n = ci >> 3;          // 0..127 (dh-global = n0+n)
      const int mc = (ci & 7) * 8;    // l-local chunk
      const half8 hv = *(const half8*)(Ct + (size_t)n * 72 + mc);
      const int n_g = n0 + n;
      const int h = n_g >> 6, dh = n_g & 63;
      const int m_g = m0 + mc;
      const int b = m_g >> 10, l = m_g & 1023;
      *(half8*)(Dvt + ((size_t)((b * 16 + h) * 64 + dh)) * 1024 + l) = hv;
    }
  }
}

// ------------------------------------------------- pipelined flash attention
// grid (LQ/64, B*H), 8 waves: qsub = wv>>1 (16 q-rows each), khalf = wv&1
// (keys 0..31 / 32..63 of the SHARED 64-key tile). KV dbuf 2 x 16 KB,
// Pt 8 x 1 KB -> 40 KB LDS, 16 waves/CU. Per-iter vmcnt(4) gate
// (2 DMA + 2 bias loads/thread). Softmax in log2 domain (bias prescaled).
__global__ __launch_bounds__(512, 4) void attn(
    const _Float16* __restrict__ Qh, const _Float16* __restrict__ Kh,
    const _Float16* __restrict__ Vt, const _Float16* __restrict__ biasC,
    _Float16* __restrict__ AO) {
  __shared__ __align__(16) _Float16 KV[2 * 8192];  // [buf][K 64x64 | V 64x64]
  __shared__ __align__(16) _Float16 Pt[8][512];    // per-wave P (16q x 32k)

  const int tid = threadIdx.x;
  const int wv = tid >> 6, ln = tid & 63;
  const int quad = ln >> 4, col = ln & 15;
  const int qsub = wv >> 1, khalf = wv & 1;
  const int q0 = blockIdx.x * 64;
  const int bh = blockIdx.y;
  const int b = bh >> 4, hh = bh & 15;
  const int qg = q0 + qsub * 16 + col;

  // Q fragments direct from global, fully drained so manual vmcnt counts stay exact
  const _Float16* Qp = Qh + ((size_t)bh * 1024 + qg) * 64;
  const half8 bq0 = *(const half8*)(Qp + quad * 8);
  const half8 bq1 = *(const half8*)(Qp + 32 + quad * 8);
  WAITCNT_VM(0);

  const _Float16* biasRow = biasC + ((size_t)(b * 1024 + qg)) * 1024;

  // stage key-block `it` (64 keys: K rows + V^T rows) -> 1024 chunks, 2/thread
  auto stageKV = [&](int buf, int it) {
    const int koff = it * 64;
#pragma unroll
    for (int j = 0; j < 2; ++j) {
      const int ci = j * 512 + tid;
      const void* src;
      if (ci < 512) {  // K tile: row = key
        const int row = ci >> 3, lc = (ci & 7) ^ (row & 7);
        src = Kh + ((size_t)bh * 1024 + koff + row) * 64 + lc * 8;
      } else {         // V tile: row = dh
        const int di = ci - 512;
        const int row = di >> 3, lc = (di & 7) ^ (row & 7);
        src = Vt + ((size_t)bh * 64 + row) * 1024 + koff + lc * 8;
      }
      gload16(src, KV + buf * 8192 + (j * 512 + wv * 64) * 8);
    }
  };
  auto loadBias = [&](int it, half4_t* bb) {
    const int koff = it * 64 + khalf * 32;
#pragma unroll
    for (int mi = 0; mi < 2; ++mi)
      bb[mi] = *(const half4_t*)&biasRow[koff + mi * 16 + quad * 4];
  };

  const f32x4 zero4 = {0.f, 0.f, 0.f, 0.f};
  f32x4 o[4];
#pragma unroll
  for (int ni = 0; ni < 4; ++ni) o[ni] = zero4;
  float m_i = -1e30f, l_i = 0.f;
  _Float16* Pw = Pt[wv];

  // one 32-key half-tile: S^T -> bias(add) -> online softmax (base-2) -> P -> O^T
  auto compute = [&](int buf, const half4_t* bb) {
    const _Float16* Ks = KV + buf * 8192;
    const _Float16* Vs = Ks + 4096;
    f32x4 s[2];
#pragma unroll
    for (int mi = 0; mi < 2; ++mi) {
      f32x4 a4 = zero4;
      a4 = MFMA16(frag_ld(Ks, khalf * 32 + mi * 16 + col, quad), bq0, a4);
      a4 = MFMA16(frag_ld(Ks, khalf * 32 + mi * 16 + col, 4 + quad), bq1, a4);
      s[mi] = a4;
    }
#pragma unroll
    for (int mi = 0; mi < 2; ++mi)
#pragma unroll
      for (int r = 0; r < 4; ++r)
        s[mi][r] = s[mi][r] * 0.18033688f + (float)bb[mi][r];  // 0.125*log2(e); bias premasked+prescaled
    float rm = fmaxf(fmaxf(fmaxf(s[0][0], s[0][1]), fmaxf(s[0][2], s[0][3])),
                     fmaxf(fmaxf(s[1][0], s[1][1]), fmaxf(s[1][2], s[1][3])));
    rm = fmaxf(rm, __shfl_xor(rm, 16));
    rm = fmaxf(rm, __shfl_xor(rm, 32));
    const float mn = fmaxf(m_i, rm);
    const float alpha = EXP2F(m_i - mn);
    m_i = mn;
    float ps = 0.f;
#pragma unroll
    for (int mi = 0; mi < 2; ++mi)
#pragma unroll
      for (int r = 0; r < 4; ++r) {
        const float p = EXP2F(s[mi][r] - mn);
        s[mi][r] = p;
        ps += p;
      }
    ps += __shfl_xor(ps, 16);
    ps += __shfl_xor(ps, 32);
    l_i = l_i * alpha + ps;
#pragma unroll
    for (int ni = 0; ni < 4; ++ni)
#pragma unroll
      for (int r = 0; r < 4; ++r) o[ni][r] *= alpha;
    // P roundtrip: rows of 32 halves (4 chunks), physical chunk = logical ^ (col&3)
#pragma unroll
    for (int mi = 0; mi < 2; ++mi) {
      half4_t h;
      h[0] = (_Float16)s[mi][0]; h[1] = (_Float16)s[mi][1];
      h[2] = (_Float16)s[mi][2]; h[3] = (_Float16)s[mi][3];
      const int kloc = mi * 16 + quad * 4;
      *(half4_t*)(Pw + col * 32 + ((((kloc >> 3) ^ (col & 3)) << 3) | (kloc & 7))) = h;
    }
    const half8 p0 = *(const half8*)(Pw + col * 32 + ((quad ^ (col & 3)) << 3));
#pragma unroll
    for (int ni = 0; ni < 4; ++ni)
      o[ni] = MFMA16(frag_ld(Vs, ni * 16 + col, khalf * 4 + quad), p0, o[ni]);
  };

  half4_t bbA[2], bbB[2];
  stageKV(0, 0);
  loadBias(0, bbA);
  for (int i = 0; i < 15; ++i) {
    stageKV((i + 1) & 1, i + 1);
    loadBias(i + 1, bbB);
    WAITCNT_VM(4);   // tile-i DMA + bias-i landed; i+1 (4 ops) in flight
    RAW_BARRIER();
    compute(i & 1, bbA);
    WAITCNT_LGKM0();
    RAW_BARRIER();   // all waves done reading buf (i&1)
    bbA[0] = bbB[0]; bbA[1] = bbB[1];
  }
  WAITCNT_VM(0);
  RAW_BARRIER();
  compute(1, bbA);   // tile 15, buffer 1

  // split-K merge (khalf 1 -> LDS -> khalf 0), then write AO
  __syncthreads();
  f32x4* Ox = (f32x4*)&KV[0];      // 16 KB (KV dead): [qsub][ni][ln]
  float* MlS = (float*)&KV[8192];  // byte 16384: [2][qsub][64]
  if (khalf == 1) {
#pragma unroll
    for (int ni = 0; ni < 4; ++ni) Ox[(qsub * 4 + ni) * 64 + ln] = o[ni];
    MlS[qsub * 64 + ln] = m_i;
    MlS[256 + qsub * 64 + ln] = l_i;
  }
  __syncthreads();
  if (khalf == 0) {
    const float m2 = MlS[qsub * 64 + ln];
    const float l2 = MlS[256 + qsub * 64 + ln];
    const float ms = fmaxf(m_i, m2);
    const float w1 = EXP2F(m_i - ms);
    const float w2 = EXP2F(m2 - ms);
    const float inv = 1.0f / (l_i * w1 + l2 * w2);
#pragma unroll
    for (int ni = 0; ni < 4; ++ni) {
      const f32x4 o2 = Ox[(qsub * 4 + ni) * 64 + ln];
      half4_t h;
#pragma unroll
      for (int r = 0; r < 4; ++r)
        h[r] = (_Float16)((o[ni][r] * w1 + o2[r] * w2) * inv);
      *(half4_t*)&AO[((size_t)(b * 1024 + qg)) * 1024 + hh * 64 + ni * 16 + quad * 4] = h;
    }
  }
}

extern "C" void kernel_launch(void* const* d_in, const int* in_sizes, int n_in,
                              void* d_out, int out_size, void* d_ws, size_t ws_size,
                              hipStream_t stream) {
  (void)in_sizes; (void)n_in; (void)out_size; (void)ws_size;
  const float* q = (const float*)d_in[0];
  const float* k = (const float*)d_in[1];
  const float* v = (const float*)d_in[2];
  const float* Wq = (const float*)d_in[3];
  const float* bq = (const float*)d_in[4];
  const float* Wk = (const float*)d_in[5];
  const float* bk = (const float*)d_in[6];
  const float* Wv = (const float*)d_in[7];
  const float* bv = (const float*)d_in[8];
  const float* Wo = (const float*)d_in[9];
  const float* bo = (const float*)d_in[10];
  const float* lb = (const float*)d_in[11];
  const int* kpm = (const int*)d_in[12];
  float* out = (float*)d_out;

  const size_t NT = (size_t)2 * 1024 * 1024;
  _Float16* q16 = (_Float16*)d_ws;
  _Float16* k16 = q16 + NT;
  _Float16* v16 = k16 + NT;
  _Float16* Qh = v16 + NT;
  _Float16* Kh = Qh + NT;
  _Float16* Vt = Kh + NT;
  _Float16* w16 = Vt + NT;  // 4 x 1M halves (Wq,Wk,Wv,Wo)
  _Float16* AO = q16;       // q16 dead after projections
  _Float16* biasC = k16;    // k16 dead after projections (4 MB = 2M halves)

  cvt_f32_f16<<<dim3(1024, 7), 256, 0, stream>>>(q, k, v, Wq, Wk, Wv, Wo,
                                                 q16, k16, v16, w16);
  mmp<<<dim3(8, 32, 3), 256, 0, stream>>>(q16, k16, v16, w16, bq, bk, bv,
                                          Qh, Kh, Vt, nullptr, 0);
  cvt_bias<<<dim3(1024), 256, 0, stream>>>(lb, kpm, biasC);
  attn<<<dim3(16, 32), 512, 0, stream>>>(Qh, Kh, Vt, biasC, AO);
  mmp<<<dim3(8, 32, 1), 256, 0, stream>>>(AO, nullptr, nullptr, w16 + 3 * NT / 2,
                                          bo, nullptr, nullptr, nullptr, nullptr,
                                          nullptr, out, 1);
}

// Round 2
// 170.072 us; speedup vs baseline: 1.0439x; 1.0236x over previous
//
#include <hip/hip_runtime.h>

// BiasedCrossAttention B=2, LQ=LK=1024, D=1024, H=16, DH=64. fp32 in/out.
// R8: projection GEMMs (12.9 GF, the largest remaining dispatch) moved to a
//     128x128 tile (mmp_big): 4 waves x 64x64 sub-tile -> 32 MFMA : 16 ds_read
//     per K-step (vs 16:12 in the 64x128 kernel), half the barriers per FLOP.
//     LDS 64 KB dbuf = 2 blocks/CU (m93/m97 config). Final Wo GEMM (4.3 GF)
//     keeps the 64x128 kernel (256 blocks; 128^2 would idle half the CUs).
//     cvt_bias folded into cvt_f32_f16 (y==7); biasC moved after w16 (k16 is
//     live until the projection pass reads it).
// ws (halves): q16|k16|v16|Qh|Kh|Vt (2M ea) | W16 (4x1M) | biasC (2M) = 36 MB.

typedef _Float16 half8 __attribute__((ext_vector_type(8)));
typedef _Float16 half4_t __attribute__((ext_vector_type(4)));
typedef float f32x4 __attribute__((ext_vector_type(4)));

#define MFMA16(a, b, c) __builtin_amdgcn_mfma_f32_16x16x32_f16((a), (b), (c), 0, 0, 0)

#define WAITCNT_VM(n) asm volatile("s_waitcnt vmcnt(" #n ")" ::: "memory")
#define WAITCNT_LGKM0() asm volatile("s_waitcnt lgkmcnt(0)" ::: "memory")
#define RAW_BARRIER() asm volatile("s_barrier" ::: "memory")
#define EXP2F(x) __builtin_amdgcn_exp2f(x)

__device__ __forceinline__ void gload16(const void* g, void* l) {
  __builtin_amdgcn_global_load_lds(
      (const __attribute__((address_space(1))) unsigned int*)g,
      (__attribute__((address_space(3))) unsigned int*)l, 16, 0, 0);
}

// Rows of 64 halves (8 x 16B chunks), physical chunk = logical ^ (row & 7).
__device__ __forceinline__ half8 frag_ld(const _Float16* t, int row, int ck) {
  return *(const half8*)(t + row * 64 + (((ck ^ (row & 7)) << 3)));
}

// ------------------------------------------------- cvt fp32->fp16 (acts + weights)
// y==7: bias mask-fold + log2-prescale into fp16 (softmax runs base-2).
__global__ __launch_bounds__(256) void cvt_f32_f16(
    const float* __restrict__ q, const float* __restrict__ k, const float* __restrict__ v,
    const float* __restrict__ Wq, const float* __restrict__ Wk,
    const float* __restrict__ Wv, const float* __restrict__ Wo,
    const float* __restrict__ biasL, const int* __restrict__ kpm,
    _Float16* __restrict__ q16, _Float16* __restrict__ k16, _Float16* __restrict__ v16,
    _Float16* __restrict__ w16, _Float16* __restrict__ biasC) {
  const int y = blockIdx.y;
  if (y == 7) {  // premasked bias: biasC = mask ? -30000 : bias * log2(e)
    const size_t i = ((size_t)blockIdx.x * 256 + threadIdx.x) * 8;
    const int b = (int)(i >> 20);
    const int kk = (int)(i & 1023);
    const int* mrow = kpm + (b << 10) + kk;
    const float4 b0 = *(const float4*)(biasL + i);
    const float4 b1 = *(const float4*)(biasL + i + 4);
    const int4 m0 = *(const int4*)mrow;
    const int4 m1 = *(const int4*)(mrow + 4);
    const float sc = 1.44269504f;
    half8 h;
    h[0] = m0.x ? (_Float16)-30000.f : (_Float16)(b0.x * sc);
    h[1] = m0.y ? (_Float16)-30000.f : (_Float16)(b0.y * sc);
    h[2] = m0.z ? (_Float16)-30000.f : (_Float16)(b0.z * sc);
    h[3] = m0.w ? (_Float16)-30000.f : (_Float16)(b0.w * sc);
    h[4] = m1.x ? (_Float16)-30000.f : (_Float16)(b1.x * sc);
    h[5] = m1.y ? (_Float16)-30000.f : (_Float16)(b1.y * sc);
    h[6] = m1.z ? (_Float16)-30000.f : (_Float16)(b1.z * sc);
    h[7] = m1.w ? (_Float16)-30000.f : (_Float16)(b1.w * sc);
    *(half8*)(biasC + i) = h;
    return;
  }
  if (y >= 3 && blockIdx.x >= 512) return;  // weights are 1M elems (512 blocks)
  const float* s;
  _Float16* d;
  const size_t M = (size_t)1024 * 1024;
  switch (y) {
    case 0: s = q;  d = q16; break;
    case 1: s = k;  d = k16; break;
    case 2: s = v;  d = v16; break;
    case 3: s = Wq; d = w16; break;
    case 4: s = Wk; d = w16 + M; break;
    case 5: s = Wv; d = w16 + 2 * M; break;
    default: s = Wo; d = w16 + 3 * M; break;
  }
  const size_t i = ((size_t)blockIdx.x * 256 + threadIdx.x) * 8;
  const float4 a = *(const float4*)(s + i);
  const float4 bvv = *(const float4*)(s + i + 4);
  half8 h;
  h[0] = (_Float16)a.x; h[1] = (_Float16)a.y; h[2] = (_Float16)a.z; h[3] = (_Float16)a.w;
  h[4] = (_Float16)bvv.x; h[5] = (_Float16)bvv.y; h[6] = (_Float16)bvv.z; h[7] = (_Float16)bvv.w;
  *(half8*)(d + i) = h;
}

// ------------------------------------------------- 128x128 projection GEMM
// C = X @ W^T + bias, BM=BN=128, BK=64, 4 waves (2x2): wave tile 64x64
// (4x4 MFMA tiles, 32 MFMA : 16 ds_read_b128 per K-step). LDS 64 KB dbuf
// = 2 blocks/CU. Per-iter vmcnt(8) gate (8 DMA/thread). grid (8,16,3).
__global__ __launch_bounds__(256, 2) void mmp_big(
    const _Float16* __restrict__ Aq, const _Float16* __restrict__ Ak,
    const _Float16* __restrict__ Av, const _Float16* __restrict__ W16,
    const float* __restrict__ c0, const float* __restrict__ c1,
    const float* __restrict__ c2, _Float16* __restrict__ Dq,
    _Float16* __restrict__ Dk, _Float16* __restrict__ Dvt) {
  __shared__ __align__(16) _Float16 lds[32768];  // 2 x (A 8192 | B 8192); z==2 reuse Ct[128][136]

  const int tid = threadIdx.x;
  const int wv = tid >> 6, ln = tid & 63;
  const int quad = ln >> 4, col = ln & 15;
  const int wm = wv >> 1, wn = wv & 1;
  const int n0 = blockIdx.x * 128;
  const int m0 = blockIdx.y * 128;
  const int z = blockIdx.z;

  const _Float16* A = (z == 0) ? Aq : (z == 1) ? Ak : Av;
  const _Float16* Bw = W16 + (size_t)z * 1024 * 1024;
  const float* bias = (z == 0) ? c0 : (z == 1) ? c1 : c2;

  // stage tile k0: chunks 0..1023 = A (128 rows), 1024..2047 = B (128 rows)
  auto stage = [&](int buf, int k0) {
#pragma unroll
    for (int j = 0; j < 8; ++j) {
      const int ci = j * 256 + tid;
      const _Float16* src;
      if (ci < 1024) {
        const int row = ci >> 3, lc = (ci & 7) ^ (row & 7);
        src = A + (size_t)(m0 + row) * 1024 + k0 + lc * 8;
      } else {
        const int di = ci - 1024;
        const int row = di >> 3, lc = (di & 7) ^ (row & 7);
        src = Bw + (size_t)(n0 + row) * 1024 + k0 + lc * 8;
      }
      gload16(src, lds + buf * 16384 + (j * 256 + wv * 64) * 8);  // A at +0, B at +8192
    }
  };

  const f32x4 zero4 = {0.f, 0.f, 0.f, 0.f};
  f32x4 acc[4][4];
#pragma unroll
  for (int i = 0; i < 4; ++i)
#pragma unroll
    for (int j = 0; j < 4; ++j) acc[i][j] = zero4;

  stage(0, 0);
  for (int i = 0; i < 15; ++i) {
    stage((i + 1) & 1, (i + 1) * 64);
    WAITCNT_VM(8);   // tile i landed (this wave); prefetch i+1 stays in flight
    RAW_BARRIER();   // tile i landed for all waves
    const _Float16* As = lds + (i & 1) * 16384;
    const _Float16* Bs = As + 8192;
    half8 af0[4], bf0[4], af1[4], bf1[4];
#pragma unroll
    for (int mi = 0; mi < 4; ++mi) af0[mi] = frag_ld(As, wm * 64 + mi * 16 + col, quad);
#pragma unroll
    for (int ni = 0; ni < 4; ++ni) bf0[ni] = frag_ld(Bs, wn * 64 + ni * 16 + col, quad);
#pragma unroll
    for (int mi = 0; mi < 4; ++mi) af1[mi] = frag_ld(As, wm * 64 + mi * 16 + col, 4 + quad);
#pragma unroll
    for (int ni = 0; ni < 4; ++ni) bf1[ni] = frag_ld(Bs, wn * 64 + ni * 16 + col, 4 + quad);
    WAITCNT_LGKM0();
    RAW_BARRIER();   // all waves done reading buf (i&1) -> safe to DMA next iter
#pragma unroll
    for (int mi = 0; mi < 4; ++mi)
#pragma unroll
      for (int ni = 0; ni < 4; ++ni)
        acc[mi][ni] = MFMA16(af0[mi], bf0[ni], acc[mi][ni]);
#pragma unroll
    for (int mi = 0; mi < 4; ++mi)
#pragma unroll
      for (int ni = 0; ni < 4; ++ni)
        acc[mi][ni] = MFMA16(af1[mi], bf1[ni], acc[mi][ni]);
  }
  {  // last tile (15), buffer 1; no further staging
    WAITCNT_VM(0);
    RAW_BARRIER();
    const _Float16* As = lds + 16384;
    const _Float16* Bs = As + 8192;
    half8 af0[4], bf0[4], af1[4], bf1[4];
#pragma unroll
    for (int mi = 0; mi < 4; ++mi) af0[mi] = frag_ld(As, wm * 64 + mi * 16 + col, quad);
#pragma unroll
    for (int ni = 0; ni < 4; ++ni) bf0[ni] = frag_ld(Bs, wn * 64 + ni * 16 + col, quad);
#pragma unroll
    for (int mi = 0; mi < 4; ++mi) af1[mi] = frag_ld(As, wm * 64 + mi * 16 + col, 4 + quad);
#pragma unroll
    for (int ni = 0; ni < 4; ++ni) bf1[ni] = frag_ld(Bs, wn * 64 + ni * 16 + col, 4 + quad);
#pragma unroll
    for (int mi = 0; mi < 4; ++mi)
#pragma unroll
      for (int ni = 0; ni < 4; ++ni)
        acc[mi][ni] = MFMA16(af0[mi], bf0[ni], acc[mi][ni]);
#pragma unroll
    for (int mi = 0; mi < 4; ++mi)
#pragma unroll
      for (int ni = 0; ni < 4; ++ni)
        acc[mi][ni] = MFMA16(af1[mi], bf1[ni], acc[mi][ni]);
  }

  float bv[4];
#pragma unroll
  for (int ni = 0; ni < 4; ++ni) bv[ni] = bias[n0 + wn * 64 + ni * 16 + col];

  if (z < 2) {
    _Float16* D = z ? Dk : Dq;
#pragma unroll
    for (int mi = 0; mi < 4; ++mi) {
      const int m_g = m0 + wm * 64 + mi * 16 + quad * 4;
#pragma unroll
      for (int ni = 0; ni < 4; ++ni) {
        const int n_g = n0 + wn * 64 + ni * 16 + col;
        const int h = n_g >> 6, dh = n_g & 63;
#pragma unroll
        for (int r = 0; r < 4; ++r) {
          const int b = (m_g + r) >> 10, l = (m_g + r) & 1023;
          D[((size_t)((b * 16 + h) * 1024) + l) * 64 + dh] =
              (_Float16)(acc[mi][ni][r] + bv[ni]);
        }
      }
    }
  } else {
    // transpose 128x128 through LDS -> Vt[bh][dh][l]
    __syncthreads();
    _Float16* Ct = lds;  // [128 n][136], 272B row stride keeps 16B alignment
#pragma unroll
    for (int mi = 0; mi < 4; ++mi) {
      const int ml = wm * 64 + mi * 16 + quad * 4;
#pragma unroll
      for (int ni = 0; ni < 4; ++ni) {
        const int nl = wn * 64 + ni * 16 + col;
        half4_t h;
#pragma unroll
        for (int r = 0; r < 4; ++r) h[r] = (_Float16)(acc[mi][ni][r] + bv[ni]);
        *(half4_t*)(Ct + (size_t)nl * 136 + ml) = h;
      }
    }
    __syncthreads();
#pragma unroll
    for (int it = 0; it < 8; ++it) {
      const int ci = it * 256 + tid;
      const int n = ci >> 4;          // 0..127 (dh-global = n0+n)
      const int mc = (ci & 15) * 8;   // l-local chunk
      const half8 hv = *(const half8*)(Ct + (size_t)n * 136 + mc);
      const int n_g = n0 + n;
      const int h = n_g >> 6, dh = n_g & 63;
      const int m_g = m0 + mc;
      const int b = m_g >> 10, l = m_g & 1023;
      *(half8*)(Dvt + ((size_t)((b * 16 + h) * 64 + dh)) * 1024 + l) = hv;
    }
  }
}

// ------------------------------------------------- 64x128 GEMM (final Wo proj)
// BM=64, BN=128, BK=64, 4 waves (2x2): wave tile 32x64 (2x4 MFMA tiles).
// Double-buffered LDS (48 KB = 3 blocks/CU); per-iter vmcnt(6) gate.
__global__ __launch_bounds__(256) void mmp(
    const _Float16* __restrict__ Aq, const _Float16* __restrict__ Ak,
    const _Float16* __restrict__ Av, const _Float16* __restrict__ W16,
    const float* __restrict__ c0, const float* __restrict__ c1,
    const float* __restrict__ c2, _Float16* __restrict__ Dq,
    _Float16* __restrict__ Dk, _Float16* __restrict__ Dvt,
    float* __restrict__ Df, int is_final) {
  __shared__ __align__(16) _Float16 lds[24576];  // 2 x (A 4096 | B 8192)

  const int tid = threadIdx.x;
  const int wv = tid >> 6, ln = tid & 63;
  const int quad = ln >> 4, col = ln & 15;
  const int wm = wv >> 1, wn = wv & 1;
  const int n0 = blockIdx.x * 128;
  const int m0 = blockIdx.y * 64;
  const int z = blockIdx.z;

  const _Float16* A = (z == 0) ? Aq : (z == 1) ? Ak : Av;
  const _Float16* Bw = W16 + (size_t)z * 1024 * 1024;
  const float* bias = (z == 0) ? c0 : (z == 1) ? c1 : c2;

  auto stage = [&](int buf, int k0) {
#pragma unroll
    for (int j = 0; j < 6; ++j) {
      const int ci = j * 256 + tid;
      const _Float16* src;
      if (ci < 512) {
        const int row = ci >> 3, lc = (ci & 7) ^ (row & 7);
        src = A + (size_t)(m0 + row) * 1024 + k0 + lc * 8;
      } else {
        const int di = ci - 512;
        const int row = di >> 3, lc = (di & 7) ^ (row & 7);
        src = Bw + (size_t)(n0 + row) * 1024 + k0 + lc * 8;
      }
      gload16(src, lds + buf * 12288 + (j * 256 + wv * 64) * 8);
    }
  };

  const f32x4 zero4 = {0.f, 0.f, 0.f, 0.f};
  f32x4 acc[2][4];
#pragma unroll
  for (int i = 0; i < 2; ++i)
#pragma unroll
    for (int j = 0; j < 4; ++j) acc[i][j] = zero4;

  stage(0, 0);
  for (int i = 0; i < 15; ++i) {
    stage((i + 1) & 1, (i + 1) * 64);
    WAITCNT_VM(6);
    RAW_BARRIER();
    const _Float16* As = lds + (i & 1) * 12288;
    const _Float16* Bs = As + 4096;
    half8 af[2][2], bf[2][4];
#pragma unroll
    for (int kk = 0; kk < 2; ++kk) {
#pragma unroll
      for (int mi = 0; mi < 2; ++mi)
        af[kk][mi] = frag_ld(As, wm * 32 + mi * 16 + col, kk * 4 + quad);
#pragma unroll
      for (int ni = 0; ni < 4; ++ni)
        bf[kk][ni] = frag_ld(Bs, wn * 64 + ni * 16 + col, kk * 4 + quad);
    }
    WAITCNT_LGKM0();
    RAW_BARRIER();
#pragma unroll
    for (int kk = 0; kk < 2; ++kk)
#pragma unroll
      for (int mi = 0; mi < 2; ++mi)
#pragma unroll
        for (int ni = 0; ni < 4; ++ni)
          acc[mi][ni] = MFMA16(af[kk][mi], bf[kk][ni], acc[mi][ni]);
  }
  {
    WAITCNT_VM(0);
    RAW_BARRIER();
    const _Float16* As = lds + 12288;
    const _Float16* Bs = As + 4096;
#pragma unroll
    for (int kk = 0; kk < 2; ++kk) {
      half8 af[2], bf[4];
#pragma unroll
      for (int mi = 0; mi < 2; ++mi)
        af[mi] = frag_ld(As, wm * 32 + mi * 16 + col, kk * 4 + quad);
#pragma unroll
      for (int ni = 0; ni < 4; ++ni)
        bf[ni] = frag_ld(Bs, wn * 64 + ni * 16 + col, kk * 4 + quad);
#pragma unroll
      for (int mi = 0; mi < 2; ++mi)
#pragma unroll
        for (int ni = 0; ni < 4; ++ni)
          acc[mi][ni] = MFMA16(af[mi], bf[ni], acc[mi][ni]);
    }
  }

  float bv[4];
#pragma unroll
  for (int ni = 0; ni < 4; ++ni) bv[ni] = bias[n0 + wn * 64 + ni * 16 + col];

  if (is_final) {
#pragma unroll
    for (int mi = 0; mi < 2; ++mi) {
      const int m_g = m0 + wm * 32 + mi * 16 + quad * 4;
#pragma unroll
      for (int ni = 0; ni < 4; ++ni) {
        const int n_g = n0 + wn * 64 + ni * 16 + col;
#pragma unroll
        for (int r = 0; r < 4; ++r)
          Df[(size_t)(m_g + r) * 1024 + n_g] = acc[mi][ni][r] + bv[ni];
      }
    }
  } else if (z < 2) {
    _Float16* D = z ? Dk : Dq;
#pragma unroll
    for (int mi = 0; mi < 2; ++mi) {
      const int m_g = m0 + wm * 32 + mi * 16 + quad * 4;
#pragma unroll
      for (int ni = 0; ni < 4; ++ni) {
        const int n_g = n0 + wn * 64 + ni * 16 + col;
        const int h = n_g >> 6, dh = n_g & 63;
#pragma unroll
        for (int r = 0; r < 4; ++r) {
          const int b = (m_g + r) >> 10, l = (m_g + r) & 1023;
          D[((size_t)((b * 16 + h) * 1024) + l) * 64 + dh] =
              (_Float16)(acc[mi][ni][r] + bv[ni]);
        }
      }
    }
  } else {
    __syncthreads();
    _Float16* Ct = lds;  // [128][72]
#pragma unroll
    for (int mi = 0; mi < 2; ++mi) {
      const int ml = wm * 32 + mi * 16 + quad * 4;
#pragma unroll
      for (int ni = 0; ni < 4; ++ni) {
        const int nl = wn * 64 + ni * 16 + col;
#pragma unroll
        for (int r = 0; r < 4; ++r)
          Ct[(size_t)nl * 72 + ml + r] = (_Float16)(acc[mi][ni][r] + bv[ni]);
      }
    }
    __syncthreads();
#pragma unroll
    for (int it = 0; it < 4; ++it) {
      const int ci = it * 256 + tid;
      const int n = ci >> 3;
      const int mc = (ci & 7) * 8;
      const half8 hv = *(const half8*)(Ct + (size_t)n * 72 + mc);
      const int n_g = n0 + n;
      const int h = n_g >> 6, dh = n_g & 63;
      const int m_g = m0 + mc;
      const int b = m_g >> 10, l = m_g & 1023;
      *(half8*)(Dvt + ((size_t)((b * 16 + h) * 64 + dh)) * 1024 + l) = hv;
    }
  }
}

// ------------------------------------------------- pipelined flash attention
// grid (LQ/64, B*H), 8 waves: qsub = wv>>1 (16 q-rows each), khalf = wv&1
// (keys 0..31 / 32..63 of the SHARED 64-key tile). KV dbuf 2 x 16 KB,
// Pt 8 x 1 KB -> 40 KB LDS, 16 waves/CU. Per-iter vmcnt(4) gate.
__global__ __launch_bounds__(512, 4) void attn(
    const _Float16* __restrict__ Qh, const _Float16* __restrict__ Kh,
    const _Float16* __restrict__ Vt, const _Float16* __restrict__ biasC,
    _Float16* __restrict__ AO) {
  __shared__ __align__(16) _Float16 KV[2 * 8192];  // [buf][K 64x64 | V 64x64]
  __shared__ __align__(16) _Float16 Pt[8][512];    // per-wave P (16q x 32k)

  const int tid = threadIdx.x;
  const int wv = tid >> 6, ln = tid & 63;
  const int quad = ln >> 4, col = ln & 15;
  const int qsub = wv >> 1, khalf = wv & 1;
  const int q0 = blockIdx.x * 64;
  const int bh = blockIdx.y;
  const int b = bh >> 4, hh = bh & 15;
  const int qg = q0 + qsub * 16 + col;

  const _Float16* Qp = Qh + ((size_t)bh * 1024 + qg) * 64;
  const half8 bq0 = *(const half8*)(Qp + quad * 8);
  const half8 bq1 = *(const half8*)(Qp + 32 + quad * 8);
  WAITCNT_VM(0);

  const _Float16* biasRow = biasC + ((size_t)(b * 1024 + qg)) * 1024;

  auto stageKV = [&](int buf, int it) {
    const int koff = it * 64;
#pragma unroll
    for (int j = 0; j < 2; ++j) {
      const int ci = j * 512 + tid;
      const void* src;
      if (ci < 512) {  // K tile: row = key
        const int row = ci >> 3, lc = (ci & 7) ^ (row & 7);
        src = Kh + ((size_t)bh * 1024 + koff + row) * 64 + lc * 8;
      } else {         // V tile: row = dh
        const int di = ci - 512;
        const int row = di >> 3, lc = (di & 7) ^ (row & 7);
        src = Vt + ((size_t)bh * 64 + row) * 1024 + koff + lc * 8;
      }
      gload16(src, KV + buf * 8192 + (j * 512 + wv * 64) * 8);
    }
  };
  auto loadBias = [&](int it, half4_t* bb) {
    const int koff = it * 64 + khalf * 32;
#pragma unroll
    for (int mi = 0; mi < 2; ++mi)
      bb[mi] = *(const half4_t*)&biasRow[koff + mi * 16 + quad * 4];
  };

  const f32x4 zero4 = {0.f, 0.f, 0.f, 0.f};
  f32x4 o[4];
#pragma unroll
  for (int ni = 0; ni < 4; ++ni) o[ni] = zero4;
  float m_i = -1e30f, l_i = 0.f;
  _Float16* Pw = Pt[wv];

  auto compute = [&](int buf, const half4_t* bb) {
    const _Float16* Ks = KV + buf * 8192;
    const _Float16* Vs = Ks + 4096;
    f32x4 s[2];
#pragma unroll
    for (int mi = 0; mi < 2; ++mi) {
      f32x4 a4 = zero4;
      a4 = MFMA16(frag_ld(Ks, khalf * 32 + mi * 16 + col, quad), bq0, a4);
      a4 = MFMA16(frag_ld(Ks, khalf * 32 + mi * 16 + col, 4 + quad), bq1, a4);
      s[mi] = a4;
    }
#pragma unroll
    for (int mi = 0; mi < 2; ++mi)
#pragma unroll
      for (int r = 0; r < 4; ++r)
        s[mi][r] = s[mi][r] * 0.18033688f + (float)bb[mi][r];  // 0.125*log2(e)
    float rm = fmaxf(fmaxf(fmaxf(s[0][0], s[0][1]), fmaxf(s[0][2], s[0][3])),
                     fmaxf(fmaxf(s[1][0], s[1][1]), fmaxf(s[1][2], s[1][3])));
    rm = fmaxf(rm, __shfl_xor(rm, 16));
    rm = fmaxf(rm, __shfl_xor(rm, 32));
    const float mn = fmaxf(m_i, rm);
    const float alpha = EXP2F(m_i - mn);
    m_i = mn;
    float ps = 0.f;
#pragma unroll
    for (int mi = 0; mi < 2; ++mi)
#pragma unroll
      for (int r = 0; r < 4; ++r) {
        const float p = EXP2F(s[mi][r] - mn);
        s[mi][r] = p;
        ps += p;
      }
    ps += __shfl_xor(ps, 16);
    ps += __shfl_xor(ps, 32);
    l_i = l_i * alpha + ps;
#pragma unroll
    for (int ni = 0; ni < 4; ++ni)
#pragma unroll
      for (int r = 0; r < 4; ++r) o[ni][r] *= alpha;
#pragma unroll
    for (int mi = 0; mi < 2; ++mi) {
      half4_t h;
      h[0] = (_Float16)s[mi][0]; h[1] = (_Float16)s[mi][1];
      h[2] = (_Float16)s[mi][2]; h[3] = (_Float16)s[mi][3];
      const int kloc = mi * 16 + quad * 4;
      *(half4_t*)(Pw + col * 32 + ((((kloc >> 3) ^ (col & 3)) << 3) | (kloc & 7))) = h;
    }
    const half8 p0 = *(const half8*)(Pw + col * 32 + ((quad ^ (col & 3)) << 3));
#pragma unroll
    for (int ni = 0; ni < 4; ++ni)
      o[ni] = MFMA16(frag_ld(Vs, ni * 16 + col, khalf * 4 + quad), p0, o[ni]);
  };

  half4_t bbA[2], bbB[2];
  stageKV(0, 0);
  loadBias(0, bbA);
  for (int i = 0; i < 15; ++i) {
    stageKV((i + 1) & 1, i + 1);
    loadBias(i + 1, bbB);
    WAITCNT_VM(4);
    RAW_BARRIER();
    compute(i & 1, bbA);
    WAITCNT_LGKM0();
    RAW_BARRIER();
    bbA[0] = bbB[0]; bbA[1] = bbB[1];
  }
  WAITCNT_VM(0);
  RAW_BARRIER();
  compute(1, bbA);

  __syncthreads();
  f32x4* Ox = (f32x4*)&KV[0];
  float* MlS = (float*)&KV[8192];
  if (khalf == 1) {
#pragma unroll
    for (int ni = 0; ni < 4; ++ni) Ox[(qsub * 4 + ni) * 64 + ln] = o[ni];
    MlS[qsub * 64 + ln] = m_i;
    MlS[256 + qsub * 64 + ln] = l_i;
  }
  __syncthreads();
  if (khalf == 0) {
    const float m2 = MlS[qsub * 64 + ln];
    const float l2 = MlS[256 + qsub * 64 + ln];
    const float ms = fmaxf(m_i, m2);
    const float w1 = EXP2F(m_i - ms);
    const float w2 = EXP2F(m2 - ms);
    const float inv = 1.0f / (l_i * w1 + l2 * w2);
#pragma unroll
    for (int ni = 0; ni < 4; ++ni) {
      const f32x4 o2 = Ox[(qsub * 4 + ni) * 64 + ln];
      half4_t h;
#pragma unroll
      for (int r = 0; r < 4; ++r)
        h[r] = (_Float16)((o[ni][r] * w1 + o2[r] * w2) * inv);
      *(half4_t*)&AO[((size_t)(b * 1024 + qg)) * 1024 + hh * 64 + ni * 16 + quad * 4] = h;
    }
  }
}

extern "C" void kernel_launch(void* const* d_in, const int* in_sizes, int n_in,
                              void* d_out, int out_size, void* d_ws, size_t ws_size,
                              hipStream_t stream) {
  (void)in_sizes; (void)n_in; (void)out_size; (void)ws_size;
  const float* q = (const float*)d_in[0];
  const float* k = (const float*)d_in[1];
  const float* v = (const float*)d_in[2];
  const float* Wq = (const float*)d_in[3];
  const float* bq = (const float*)d_in[4];
  const float* Wk = (const float*)d_in[5];
  const float* bk = (const float*)d_in[6];
  const float* Wv = (const float*)d_in[7];
  const float* bv = (const float*)d_in[8];
  const float* Wo = (const float*)d_in[9];
  const float* bo = (const float*)d_in[10];
  const float* lb = (const float*)d_in[11];
  const int* kpm = (const int*)d_in[12];
  float* out = (float*)d_out;

  const size_t NT = (size_t)2 * 1024 * 1024;
  _Float16* q16 = (_Float16*)d_ws;
  _Float16* k16 = q16 + NT;
  _Float16* v16 = k16 + NT;
  _Float16* Qh = v16 + NT;
  _Float16* Kh = Qh + NT;
  _Float16* Vt = Kh + NT;
  _Float16* w16 = Vt + NT;        // 4 x 1M halves (Wq,Wk,Wv,Wo)
  _Float16* biasC = w16 + 4 * (NT / 2);  // 2M halves (4 MB)
  _Float16* AO = q16;             // q16 dead after projections

  cvt_f32_f16<<<dim3(1024, 8), 256, 0, stream>>>(q, k, v, Wq, Wk, Wv, Wo, lb, kpm,
                                                 q16, k16, v16, w16, biasC);
  mmp_big<<<dim3(8, 16, 3), 256, 0, stream>>>(q16, k16, v16, w16, bq, bk, bv,
                                              Qh, Kh, Vt);
  attn<<<dim3(16, 32), 512, 0, stream>>>(Qh, Kh, Vt, biasC, AO);
  mmp<<<dim3(8, 32, 1), 256, 0, stream>>>(AO, nullptr, nullptr, w16 + 3 * NT / 2,
                                          bo, nullptr, nullptr, nullptr, nullptr,
                                          nullptr, out, 1);
}